// Round 3
// baseline (2089.870 us; speedup 1.0000x reference)
//
#include <hip/hip_runtime.h>
#include <stdint.h>

// ---------------- types / helpers ----------------
typedef short bf16x8 __attribute__((ext_vector_type(8)));
typedef float f32x4 __attribute__((ext_vector_type(4)));

#define AS1 __attribute__((address_space(1)))
#define AS3 __attribute__((address_space(3)))

static __device__ __forceinline__ void gl16(const void* g, void* l) {
  __builtin_amdgcn_global_load_lds((const AS1 void*)g, (AS3 void*)l, 16, 0, 0);
}

static __device__ __forceinline__ unsigned short f2bf(float f) {
  unsigned u = __float_as_uint(f);
  u = u + 0x7fffu + ((u >> 16) & 1u);
  return (unsigned short)(u >> 16);
}
static __device__ __forceinline__ float bf2f(unsigned short h) {
  return __uint_as_float(((unsigned)h) << 16);
}
static __device__ __forceinline__ float mishf(float x) {
  float sp = fmaxf(x, 0.f) + log1pf(expf(-fabsf(x)));
  float e2 = expf(-2.f * sp);
  float th = (1.f - e2) / (1.f + e2);
  return x * th;
}

// geometry
#define NIMG 8
#define HH 128
#define WW 128
#define HP 130
#define CIN 256
#define MPIX (NIMG * HH * WW)       // 131072
#define KTOT 2304                   // 3*768
#define FGCNT (MPIX * 9)            // 1179648
#define TSCNT (MPIX * 9 * 4)        // 4718592

__device__ __constant__ float AW[9] = {456.f, 912.f, 1824.f, 320.f, 640.f, 1280.f, 224.f, 448.f, 896.f};
__device__ __constant__ float AH[9] = {224.f, 448.f, 896.f, 320.f, 640.f, 1280.f, 448.f, 896.f, 1792.f};

// ---------------- K0a: reorder conv weights -> Wt[oc][kh*768+kw*256+ic] bf16 ----------------
__global__ __launch_bounds__(256) void k_wt(const float* __restrict__ Wb,
                                            unsigned short* __restrict__ Wt) {
  int idx = blockIdx.x * 256 + threadIdx.x;  // 256*2304 = 589824 exactly
  int oc = idx / KTOT, k = idx % KTOT;
  int kh = k / 768, r = k % 768, kw = r / 256, ic = r % 256;
  Wt[oc * KTOT + k] = f2bf(Wb[((oc * 256 + ic) * 3 + kh) * 3 + kw]);
}

// ---------------- K0b: x (NCHW f32) -> xtp (padded NHWC bf16) interior ----------------
__global__ __launch_bounds__(256) void k_tr(const float* __restrict__ x,
                                            unsigned short* __restrict__ xtp) {
  __shared__ float tile[32][129];
  int b = blockIdx.x;  // 8 n * 128 h * 8 icb = 8192
  int icb = b & 7, h = (b >> 3) & 127, n = b >> 10;
  int t = threadIdx.x;
  const float* src = x + (((size_t)(n * 256 + icb * 32) * 128 + h) * 128);
#pragma unroll
  for (int i = 0; i < 4; ++i) {
    int idx = t + 256 * i;          // 1024 float4 units
    int w4 = idx & 31, ic = idx >> 5;
    float4 v = *(const float4*)(src + (size_t)ic * 16384 + w4 * 4);
    tile[ic][w4 * 4 + 0] = v.x; tile[ic][w4 * 4 + 1] = v.y;
    tile[ic][w4 * 4 + 2] = v.z; tile[ic][w4 * 4 + 3] = v.w;
  }
  __syncthreads();
#pragma unroll
  for (int i = 0; i < 8; ++i) {
    int idx = t + 256 * i;          // 2048 bf16-pairs
    int icp = idx & 15, w = idx >> 4;
    unsigned lo = f2bf(tile[icp * 2][w]);
    unsigned hi = f2bf(tile[icp * 2 + 1][w]);
    size_t pix = ((size_t)(n * HP + h + 1) * HP + (w + 1));
    *(unsigned*)(xtp + pix * 256 + icb * 32 + icp * 2) = lo | (hi << 16);
  }
}

// ---------------- K0c: zero padded borders of xtp ----------------
__global__ __launch_bounds__(256) void k_bord(unsigned short* __restrict__ xtp) {
  int tid = blockIdx.x * 256 + threadIdx.x;  // 4128 border pixels * 32 chunks
  if (tid >= 4128 * 32) return;
  int chunk = tid & 31, pix = tid >> 5;
  int n = pix / 516, bp = pix % 516;
  int hp, wp;
  if (bp < 130) { hp = 0; wp = bp; }
  else if (bp < 260) { hp = 129; wp = bp - 130; }
  else { int r = bp - 260; hp = 1 + (r >> 1); wp = (r & 1) ? 129 : 0; }
  size_t off = ((size_t)(n * HP + hp) * HP + wp) * 256 + chunk * 8;
  uint4 z = {0u, 0u, 0u, 0u};
  *(uint4*)(xtp + off) = z;
}

// ---------------- K1: conv3x3 implicit GEMM, 256x256 tile, 8 waves ----------------
// M = 131072 pixels, N = 256 oc, K = 2304 (kh-major: 3 x (kw x ic = 768))
// LDS: k-group-subtiled [4][256][8] shorts -> 16B rows, bank-conflict-free frag reads
// (R2 verified: SQ_LDS_BANK_CONFLICT == 0), chunk id matches global_load_lds lane order.
// launch_bounds(512, 1): R2's (512,2) capped VGPR at 128 -> acc[8][4] spilled to
// scratch (VGPR_Count 84, WRITE_SIZE 9.66 GB = 262KB/block/K-step). 1 wave/EU min
// lifts the cap to 512; kernel needs ~210.
__global__ __launch_bounds__(512, 1) void k_conv(const unsigned short* __restrict__ xtp,
                                                 const unsigned short* __restrict__ Wt,
                                                 const float* __restrict__ b_base,
                                                 unsigned short* __restrict__ yt,
                                                 float* __restrict__ statsA) {
  __shared__ __align__(16) short Alds[4][256][8];
  __shared__ __align__(16) short Blds[4][256][8];
  int t = threadIdx.x;
  int lane = t & 63, w4 = t >> 6;      // 8 waves
  int wr = w4 >> 2, wc = w4 & 3;       // 2M x 4N wave grid; wave tile 128M x 64N
  int row16 = lane & 15, kgl = lane >> 4;

  // XCD-chunked swizzle: consecutive h-tiles land on the same XCD L2
  int bid = blockIdx.x;                // 512 blocks, 512 % 8 == 0
  int swz = (bid & 7) * 64 + (bid >> 3);
  int n = swz >> 6;
  int h0 = (swz & 63) * 2;
  size_t M0 = (size_t)swz * 256;

  f32x4 acc[8][4];
#pragma unroll
  for (int m = 0; m < 8; ++m)
#pragma unroll
    for (int nf = 0; nf < 4; ++nf) { f32x4 z = {0.f, 0.f, 0.f, 0.f}; acc[m][nf] = z; }

  // staging: A tile 256pix x 32k = 1024 16B-chunks; chunk c = kgrp*256 + pix.
  // thread t handles chunks t and t+512.
  int pix = t & 255;
  int kg0 = t >> 8;                    // 0..1
  int rowadd = pix >> 7, colp = pix & 127;
  const unsigned short* srcA = xtp + ((size_t)((n * HP) + h0 + rowadd) * HP + colp) * 256;
  const unsigned short* srcB = Wt + (size_t)pix * KTOT;   // pix == oc for B
  char* aldsb = (char*)&Alds[0][0][0];
  char* bldsb = (char*)&Blds[0][0][0];
  char* dstA0 = aldsb + w4 * 1024;
  char* dstA1 = aldsb + (w4 + 8) * 1024;
  char* dstB0 = bldsb + w4 * 1024;
  char* dstB1 = bldsb + (w4 + 8) * 1024;
  const size_t rowstride = (size_t)HP * 256;

  for (int s = 0; s < 72; ++s) {
    int kh = s / 24;
    int ko = (s % 24) * 32;
    size_t aoff = (size_t)kh * rowstride + ko;
    gl16(srcA + aoff + kg0 * 8, dstA0);
    gl16(srcA + aoff + (kg0 + 2) * 8, dstA1);
    size_t boff = (size_t)s * 32;
    gl16(srcB + boff + kg0 * 8, dstB0);
    gl16(srcB + boff + (kg0 + 2) * 8, dstB1);
    __syncthreads();

    bf16x8 af[8], bfr[4];
#pragma unroll
    for (int m = 0; m < 8; ++m) af[m] = *(const bf16x8*)&Alds[kgl][wr * 128 + m * 16 + row16][0];
#pragma unroll
    for (int nf = 0; nf < 4; ++nf) bfr[nf] = *(const bf16x8*)&Blds[kgl][wc * 64 + nf * 16 + row16][0];
#pragma unroll
    for (int m = 0; m < 8; ++m)
#pragma unroll
      for (int nf = 0; nf < 4; ++nf)
        acc[m][nf] = __builtin_amdgcn_mfma_f32_16x16x32_bf16(af[m], bfr[nf], acc[m][nf], 0, 0, 0);
    __syncthreads();
  }

  // epilogue: bias + mish, store NHWC bf16, per-channel sum/sumsq
  float sums[4] = {0.f, 0.f, 0.f, 0.f}, sumq[4] = {0.f, 0.f, 0.f, 0.f};
#pragma unroll
  for (int nf = 0; nf < 4; ++nf) {
    int oc = wc * 64 + nf * 16 + row16;
    float bias = b_base[oc];
#pragma unroll
    for (int m = 0; m < 8; ++m) {
#pragma unroll
      for (int j = 0; j < 4; ++j) {
        int p = wr * 128 + m * 16 + kgl * 4 + j;
        float y = mishf(acc[m][nf][j] + bias);
        yt[(M0 + p) * 256 + oc] = f2bf(y);
        sums[nf] += y; sumq[nf] += y * y;
      }
    }
  }
#pragma unroll
  for (int nf = 0; nf < 4; ++nf) {
    float s1 = sums[nf], s2 = sumq[nf];
    s1 += __shfl_xor(s1, 16); s2 += __shfl_xor(s2, 16);
    s1 += __shfl_xor(s1, 32); s2 += __shfl_xor(s2, 32);
    if (lane < 16) {
      int oc = wc * 64 + nf * 16 + lane;
      atomicAdd(&statsA[oc], s1);
      atomicAdd(&statsA[256 + oc], s2);
    }
  }
}

// ---------------- K2: finalize base BN, fold into fused 1x1 weights (64x256) ----------------
__global__ __launch_bounds__(256) void k_fold(const float* __restrict__ statsA,
                                              const float* __restrict__ g_base,
                                              const float* __restrict__ be_base,
                                              const float* __restrict__ W_cls,
                                              const float* __restrict__ b_cls,
                                              const float* __restrict__ W_reg,
                                              const float* __restrict__ b_reg,
                                              unsigned short* __restrict__ W2t,
                                              float* __restrict__ b2) {
  __shared__ float sS[256], sT[256];
  int t = threadIdx.x;
  {
    float cnt = (float)MPIX;
    float m = statsA[t] / cnt;
    float v = fmaxf(statsA[256 + t] / cnt - m * m, 0.f);
    float s = g_base[t] * rsqrtf(v + 1e-5f);
    sS[t] = s;
    sT[t] = be_base[t] - m * s;
  }
  __syncthreads();
  if (t < 64) {
    float bias = 0.f;
    if (t < 36) bias = b_reg[t];
    else if (t < 54) bias = b_cls[t - 36];
    float acc = 0.f;
    for (int ic = 0; ic < 256; ++ic) {
      float w = 0.f;
      if (t < 36) w = W_reg[t * 256 + ic];
      else if (t < 54) w = W_cls[(t - 36) * 256 + ic];
      acc += w * sT[ic];
      W2t[t * 256 + ic] = f2bf(w * sS[ic]);
    }
    b2[t] = bias + acc;
  }
}

// ---------------- K3: fused 1x1 heads GEMM (M=131072, N=64, K=256) + z stats ----------------
__global__ __launch_bounds__(256) void k_mm2(const unsigned short* __restrict__ yt,
                                             const unsigned short* __restrict__ W2t,
                                             const float* __restrict__ b2,
                                             unsigned short* __restrict__ zt,
                                             float* __restrict__ statsZ) {
  __shared__ __align__(16) short Alds[128][32];
  __shared__ __align__(16) short Blds[64][32];
  int t = threadIdx.x, lane = t & 63, w4 = t >> 6;
  size_t pixbase = (size_t)blockIdx.x * 128;

  f32x4 acc[2][4];
#pragma unroll
  for (int m = 0; m < 2; ++m)
#pragma unroll
    for (int nn = 0; nn < 4; ++nn) { f32x4 z = {0.f, 0.f, 0.f, 0.f}; acc[m][nn] = z; }

  int cA0 = (w4 * 2) * 64 + lane;
  int pA0 = cA0 >> 2, qA0 = cA0 & 3;
  int cA1 = cA0 + 64;
  int pA1 = cA1 >> 2, qA1 = cA1 & 3;
  int cB = w4 * 64 + lane;
  int oB = cB >> 2, qB = cB & 3;

  char* aldsb = (char*)&Alds[0][0];
  char* bldsb = (char*)&Blds[0][0];
  int row = lane & 15, kg = lane >> 4;

  for (int s = 0; s < 8; ++s) {
    gl16(yt + (pixbase + pA0) * 256 + s * 32 + qA0 * 8, aldsb + (w4 * 2 + 0) * 1024);
    gl16(yt + (pixbase + pA1) * 256 + s * 32 + qA1 * 8, aldsb + (w4 * 2 + 1) * 1024);
    gl16(W2t + (size_t)oB * 256 + s * 32 + qB * 8, bldsb + w4 * 1024);
    __syncthreads();
    bf16x8 af[2], bfr[4];
#pragma unroll
    for (int m = 0; m < 2; ++m) af[m] = *(const bf16x8*)&Alds[w4 * 32 + m * 16 + row][kg * 8];
#pragma unroll
    for (int nn = 0; nn < 4; ++nn) bfr[nn] = *(const bf16x8*)&Blds[nn * 16 + row][kg * 8];
#pragma unroll
    for (int m = 0; m < 2; ++m)
#pragma unroll
      for (int nn = 0; nn < 4; ++nn)
        acc[m][nn] = __builtin_amdgcn_mfma_f32_16x16x32_bf16(af[m], bfr[nn], acc[m][nn], 0, 0, 0);
    __syncthreads();
  }

  float sums[4] = {0.f, 0.f, 0.f, 0.f}, sumq[4] = {0.f, 0.f, 0.f, 0.f};
#pragma unroll
  for (int nn = 0; nn < 4; ++nn) {
    int oc = nn * 16 + row;
    float bias = b2[oc];
#pragma unroll
    for (int m = 0; m < 2; ++m) {
#pragma unroll
      for (int j = 0; j < 4; ++j) {
        int p = w4 * 32 + m * 16 + kg * 4 + j;
        float v = acc[m][nn][j] + bias;
        zt[(pixbase + p) * 64 + oc] = f2bf(v);
        sums[nn] += v; sumq[nn] += v * v;
      }
    }
  }
#pragma unroll
  for (int nn = 0; nn < 4; ++nn) {
    float s1 = sums[nn], s2 = sumq[nn];
    s1 += __shfl_xor(s1, 16); s2 += __shfl_xor(s2, 16);
    s1 += __shfl_xor(s1, 32); s2 += __shfl_xor(s2, 32);
    if (lane < 16) {
      int oc = nn * 16 + lane;
      atomicAdd(&statsZ[oc], s1);
      atomicAdd(&statsZ[64 + oc], s2);
    }
  }
}

// ---------------- K4: finalize z BN scale/shift ----------------
__global__ __launch_bounds__(64) void k_zstat(const float* __restrict__ statsZ,
                                              const float* __restrict__ g_cls,
                                              const float* __restrict__ be_cls,
                                              const float* __restrict__ g_reg,
                                              const float* __restrict__ be_reg,
                                              float* __restrict__ zsc,
                                              float* __restrict__ zsh) {
  int t = threadIdx.x;  // 64
  float g = 1.f, be = 0.f;
  if (t < 36) { g = g_reg[t]; be = be_reg[t]; }
  else if (t < 54) { g = g_cls[t - 36]; be = be_cls[t - 36]; }
  float cnt = (float)MPIX;
  float m = statsZ[t] / cnt;
  float v = fmaxf(statsZ[64 + t] / cnt - m * m, 0.f);
  float s = g * rsqrtf(v + 1e-5f);
  zsc[t] = s;
  zsh[t] = be - m * s;
}

// ---------------- K5: BN-apply + softmax + anchor decode + outputs ----------------
__global__ __launch_bounds__(256) void k_dec(const unsigned short* __restrict__ zt,
                                             const float* __restrict__ zsc,
                                             const float* __restrict__ zsh,
                                             const int* __restrict__ imgsz,
                                             float* __restrict__ out) {
  int p = blockIdx.x * 256 + threadIdx.x;  // 131072
  float lim = (float)imgsz[0];
  float zn[64];
  {
    const uint4* zp4 = (const uint4*)(zt + (size_t)p * 64);
#pragma unroll
    for (int i = 0; i < 8; ++i) {
      uint4 v = zp4[i];
      unsigned a0 = v.x, a1 = v.y, a2 = v.z, a3 = v.w;
      zn[i * 8 + 0] = bf2f((unsigned short)(a0 & 0xffff));
      zn[i * 8 + 1] = bf2f((unsigned short)(a0 >> 16));
      zn[i * 8 + 2] = bf2f((unsigned short)(a1 & 0xffff));
      zn[i * 8 + 3] = bf2f((unsigned short)(a1 >> 16));
      zn[i * 8 + 4] = bf2f((unsigned short)(a2 & 0xffff));
      zn[i * 8 + 5] = bf2f((unsigned short)(a2 >> 16));
      zn[i * 8 + 6] = bf2f((unsigned short)(a3 & 0xffff));
      zn[i * 8 + 7] = bf2f((unsigned short)(a3 >> 16));
    }
#pragma unroll
    for (int i = 0; i < 54; ++i) zn[i] = zn[i] * zsc[i] + zsh[i];
  }
  int rem = p & 16383, h = rem >> 7, w = rem & 127;
  float fx = 16.f * (float)w, fy = 16.f * (float)h;
  size_t kbase = (size_t)p * 9;
  float* fgout = out;
  float* tsout = out + FGCNT;
  float* roout = out + FGCNT + TSCNT;
#pragma unroll
  for (int a = 0; a < 9; ++a) {
    float x1 = 20.f - 0.5f * AW[a] + fx;
    float y1 = 20.f - 0.5f * AH[a] + fy;
    float x2 = 19.f + 0.5f * AW[a] + fx;
    float y2 = 19.f + 0.5f * AH[a] + fy;
    float cx1 = fminf(fmaxf(x1 + zn[4 * a + 0], 0.f), lim);
    float cy1 = fminf(fmaxf(y1 + zn[4 * a + 1], 0.f), lim);
    float cx2 = fminf(fmaxf(x2 + zn[4 * a + 2], 0.f), lim);
    float cy2 = fminf(fmaxf(y2 + zn[4 * a + 3], 0.f), lim);
    float bw = cx2 - cx1, bh = cy2 - cy1;
    float cx = cx1 + 0.5f * bw, cy = cy1 + 0.5f * bh;
    float aw = AW[a] - 1.f, ah = AH[a] - 1.f;
    float acx = 19.5f + fx, acy = 19.5f + fy;
    float tx = (cx - acx) / aw, ty = (cy - acy) / ah;
    float tw = logf(fmaxf(bw / aw, 1e-30f));
    float th = logf(fmaxf(bh / ah, 1e-30f));
    float s0 = zn[36 + 2 * a], s1 = zn[36 + 2 * a + 1];
    float fg = 1.f / (1.f + expf(s0 - s1));
    fgout[kbase + a] = fg;
    size_t o4 = (kbase + a) * 4;
    tsout[o4 + 0] = tx; tsout[o4 + 1] = ty; tsout[o4 + 2] = tw; tsout[o4 + 3] = th;
    roout[o4 + 0] = cx; roout[o4 + 1] = cy; roout[o4 + 2] = bw; roout[o4 + 3] = bh;
  }
}

// ---------------- launch ----------------
extern "C" void kernel_launch(void* const* d_in, const int* in_sizes, int n_in,
                              void* d_out, int out_size, void* d_ws, size_t ws_size,
                              hipStream_t stream) {
  const float* x   = (const float*)d_in[0];
  const float* Wb  = (const float*)d_in[1];
  const float* bb  = (const float*)d_in[2];
  const float* gb  = (const float*)d_in[3];
  const float* beb = (const float*)d_in[4];
  const float* Wc  = (const float*)d_in[5];
  const float* bc  = (const float*)d_in[6];
  const float* gc  = (const float*)d_in[7];
  const float* bec = (const float*)d_in[8];
  const float* Wr  = (const float*)d_in[9];
  const float* br  = (const float*)d_in[10];
  const float* gr  = (const float*)d_in[11];
  const float* ber = (const float*)d_in[12];
  const int* imgsz = (const int*)d_in[13];

  char* ws = (char*)d_ws;
  const size_t OFF_XTP = 0;                        // 8*130*130*256*2 = 69,222,400
  const size_t OFF_Y   = 69222400;                 // 131072*256*2    = 67,108,864
  const size_t OFF_Z   = 136331264;                // 131072*64*2     = 16,777,216
  const size_t OFF_WT  = 153108480;                // 256*2304*2      =  1,179,648
  const size_t OFF_W2  = 154288128;                // 64*256*2        =     32,768
  const size_t OFF_S   = 154320896;                // small area
  unsigned short* xtp = (unsigned short*)(ws + OFF_XTP);
  unsigned short* yt  = (unsigned short*)(ws + OFF_Y);
  unsigned short* zt  = (unsigned short*)(ws + OFF_Z);
  unsigned short* Wt  = (unsigned short*)(ws + OFF_WT);
  unsigned short* W2t = (unsigned short*)(ws + OFF_W2);
  float* b2     = (float*)(ws + OFF_S);            // 64 f
  float* statsA = (float*)(ws + OFF_S + 256);      // 512 f
  float* statsZ = (float*)(ws + OFF_S + 2304);     // 128 f
  float* zsc    = (float*)(ws + OFF_S + 2816);     // 64 f
  float* zsh    = (float*)(ws + OFF_S + 3072);     // 64 f
  float* out = (float*)d_out;

  hipMemsetAsync(statsA, 0, (512 + 128) * sizeof(float), stream);
  k_wt  <<<2304, 256, 0, stream>>>(Wb, Wt);
  k_tr  <<<8192, 256, 0, stream>>>(x, xtp);
  k_bord<<<516, 256, 0, stream>>>(xtp);
  k_conv<<<512, 512, 0, stream>>>(xtp, Wt, bb, yt, statsA);
  k_fold<<<1, 256, 0, stream>>>(statsA, gb, beb, Wc, bc, Wr, br, W2t, b2);
  k_mm2 <<<1024, 256, 0, stream>>>(yt, W2t, b2, zt, statsZ);
  k_zstat<<<1, 64, 0, stream>>>(statsZ, gc, bec, gr, ber, zsc, zsh);
  k_dec <<<512, 256, 0, stream>>>(zt, zsc, zsh, imgsz, out);
}

// Round 4
// 685.139 us; speedup vs baseline: 3.0503x; 3.0503x over previous
//
#include <hip/hip_runtime.h>
#include <stdint.h>

// ---------------- types / helpers ----------------
typedef short bf16x8 __attribute__((ext_vector_type(8)));
typedef float f32x4 __attribute__((ext_vector_type(4)));

#define AS1 __attribute__((address_space(1)))
#define AS3 __attribute__((address_space(3)))

static __device__ __forceinline__ void gl16(const void* g, void* l) {
  __builtin_amdgcn_global_load_lds((const AS1 void*)g, (AS3 void*)l, 16, 0, 0);
}

static __device__ __forceinline__ unsigned short f2bf(float f) {
  unsigned u = __float_as_uint(f);
  u = u + 0x7fffu + ((u >> 16) & 1u);
  return (unsigned short)(u >> 16);
}
static __device__ __forceinline__ float bf2f(unsigned short h) {
  return __uint_as_float(((unsigned)h) << 16);
}
static __device__ __forceinline__ float mishf(float x) {
  float sp = fmaxf(x, 0.f) + log1pf(expf(-fabsf(x)));
  float e2 = expf(-2.f * sp);
  float th = (1.f - e2) / (1.f + e2);
  return x * th;
}

// geometry
#define NIMG 8
#define HH 128
#define WW 128
#define HP 130
#define CIN 256
#define MPIX (NIMG * HH * WW)       // 131072
#define KTOT 2304                   // 3*768
#define FGCNT (MPIX * 9)            // 1179648
#define TSCNT (MPIX * 9 * 4)        // 4718592

__device__ __constant__ float AW[9] = {456.f, 912.f, 1824.f, 320.f, 640.f, 1280.f, 224.f, 448.f, 896.f};
__device__ __constant__ float AH[9] = {224.f, 448.f, 896.f, 320.f, 640.f, 1280.f, 448.f, 896.f, 1792.f};

// ---------------- K0a: reorder conv weights -> Wt[oc][kh*768+kw*256+ic] bf16 ----------------
__global__ __launch_bounds__(256) void k_wt(const float* __restrict__ Wb,
                                            unsigned short* __restrict__ Wt) {
  int idx = blockIdx.x * 256 + threadIdx.x;  // 256*2304 = 589824 exactly
  int oc = idx / KTOT, k = idx % KTOT;
  int kh = k / 768, r = k % 768, kw = r / 256, ic = r % 256;
  Wt[oc * KTOT + k] = f2bf(Wb[((oc * 256 + ic) * 3 + kh) * 3 + kw]);
}

// ---------------- K0b: x (NCHW f32) -> xtp (padded NHWC bf16) interior ----------------
__global__ __launch_bounds__(256) void k_tr(const float* __restrict__ x,
                                            unsigned short* __restrict__ xtp) {
  __shared__ float tile[32][129];
  int b = blockIdx.x;  // 8 n * 128 h * 8 icb = 8192
  int icb = b & 7, h = (b >> 3) & 127, n = b >> 10;
  int t = threadIdx.x;
  const float* src = x + (((size_t)(n * 256 + icb * 32) * 128 + h) * 128);
#pragma unroll
  for (int i = 0; i < 4; ++i) {
    int idx = t + 256 * i;          // 1024 float4 units
    int w4 = idx & 31, ic = idx >> 5;
    float4 v = *(const float4*)(src + (size_t)ic * 16384 + w4 * 4);
    tile[ic][w4 * 4 + 0] = v.x; tile[ic][w4 * 4 + 1] = v.y;
    tile[ic][w4 * 4 + 2] = v.z; tile[ic][w4 * 4 + 3] = v.w;
  }
  __syncthreads();
#pragma unroll
  for (int i = 0; i < 8; ++i) {
    int idx = t + 256 * i;          // 2048 bf16-pairs
    int icp = idx & 15, w = idx >> 4;
    unsigned lo = f2bf(tile[icp * 2][w]);
    unsigned hi = f2bf(tile[icp * 2 + 1][w]);
    size_t pix = ((size_t)(n * HP + h + 1) * HP + (w + 1));
    *(unsigned*)(xtp + pix * 256 + icb * 32 + icp * 2) = lo | (hi << 16);
  }
}

// ---------------- K0c: zero padded borders of xtp ----------------
__global__ __launch_bounds__(256) void k_bord(unsigned short* __restrict__ xtp) {
  int tid = blockIdx.x * 256 + threadIdx.x;  // 4128 border pixels * 32 chunks
  if (tid >= 4128 * 32) return;
  int chunk = tid & 31, pix = tid >> 5;
  int n = pix / 516, bp = pix % 516;
  int hp, wp;
  if (bp < 130) { hp = 0; wp = bp; }
  else if (bp < 260) { hp = 129; wp = bp - 130; }
  else { int r = bp - 260; hp = 1 + (r >> 1); wp = (r & 1) ? 129 : 0; }
  size_t off = ((size_t)(n * HP + hp) * HP + wp) * 256 + chunk * 8;
  uint4 z = {0u, 0u, 0u, 0u};
  *(uint4*)(xtp + off) = z;
}

// ---------------- K1: conv3x3 implicit GEMM ----------------
// M = 131072 pixels, N = 256 oc, K = 2304 (kh-major: 3 x (kw x ic = 768)).
// Tile: BM=128 (one output row) x BN=256 (ALL oc -> A fetched once per row).
// 8 waves, 2M x 4N grid, wave tile 64x64 -> acc[4][4] = 64 f32/thread.
//   (R2/R3 lesson: acc[8][4]=128 f32/thread spills regardless of launch_bounds
//    -> 9.66 GB scratch writes; 64/thread (R1) does not.)
// LDS: k-subtiled [4][rows][8] shorts, conflict-free (R2: SQ_LDS_BANK_CONFLICT=0),
// chunk id == global_load_lds lane order (linear dest).
__global__ __launch_bounds__(512) void k_conv(const unsigned short* __restrict__ xtp,
                                              const unsigned short* __restrict__ Wt,
                                              const float* __restrict__ b_base,
                                              unsigned short* __restrict__ yt,
                                              float* __restrict__ statsA) {
  __shared__ __align__(16) short Alds[4][128][8];   // 8 KB
  __shared__ __align__(16) short Blds[4][256][8];   // 16 KB
  int t = threadIdx.x;
  int lane = t & 63, w4 = t >> 6;      // 8 waves
  int wr = w4 >> 2, wc = w4 & 3;       // 2M x 4N wave grid
  int row16 = lane & 15, kgl = lane >> 4;

  // XCD-chunked swizzle: consecutive h-rows land on the same XCD L2
  int bid = blockIdx.x;                // 1024 blocks, 1024 % 8 == 0
  int swz = (bid & 7) * 128 + (bid >> 3);
  int n = swz >> 7;
  int h0 = swz & 127;
  size_t M0 = (size_t)swz * 128;

  f32x4 acc[4][4];
#pragma unroll
  for (int m = 0; m < 4; ++m)
#pragma unroll
    for (int nf = 0; nf < 4; ++nf) { f32x4 z = {0.f, 0.f, 0.f, 0.f}; acc[m][nf] = z; }

  // staging: A = 512 16B-chunks (chunk c: kgA=c>>7, pixA=c&127), 1 per thread;
  //          B = 1024 chunks (chunk c: kgB=c>>8, ocB=c&255), 2 per thread.
  int pixA = t & 127, kgA = t >> 7;    // kgA 0..3
  int ocB = t & 255, kgB = t >> 8;     // kgB 0..1, second chunk kgB+2
  const unsigned short* sA = xtp + ((size_t)(n * HP + h0) * HP + pixA) * 256 + kgA * 8;
  const unsigned short* sB0 = Wt + (size_t)ocB * KTOT + kgB * 8;
  const unsigned short* sB1 = sB0 + 16;          // (kgB+2)*8
  char* aldsb = (char*)&Alds[0][0][0];
  char* bldsb = (char*)&Blds[0][0][0];
  char* dA  = aldsb + w4 * 1024;
  char* dB0 = bldsb + w4 * 1024;
  char* dB1 = bldsb + 8192 + w4 * 1024;
  const size_t rowstride = (size_t)HP * 256;

  for (int s = 0; s < 72; ++s) {
    int kh = s / 24;
    int ko = (s % 24) * 32;
    gl16(sA + (size_t)kh * rowstride + ko, dA);
    int bo = s * 32;
    gl16(sB0 + bo, dB0);
    gl16(sB1 + bo, dB1);
    __syncthreads();

    bf16x8 af[4], bfr[4];
#pragma unroll
    for (int m = 0; m < 4; ++m) af[m] = *(const bf16x8*)&Alds[kgl][wr * 64 + m * 16 + row16][0];
#pragma unroll
    for (int nf = 0; nf < 4; ++nf) bfr[nf] = *(const bf16x8*)&Blds[kgl][wc * 64 + nf * 16 + row16][0];
#pragma unroll
    for (int m = 0; m < 4; ++m)
#pragma unroll
      for (int nf = 0; nf < 4; ++nf)
        acc[m][nf] = __builtin_amdgcn_mfma_f32_16x16x32_bf16(af[m], bfr[nf], acc[m][nf], 0, 0, 0);
    __syncthreads();
  }

  // epilogue: bias + mish, store NHWC bf16, per-channel sum/sumsq
  float sums[4] = {0.f, 0.f, 0.f, 0.f}, sumq[4] = {0.f, 0.f, 0.f, 0.f};
#pragma unroll
  for (int nf = 0; nf < 4; ++nf) {
    int oc = wc * 64 + nf * 16 + row16;
    float bias = b_base[oc];
#pragma unroll
    for (int m = 0; m < 4; ++m) {
#pragma unroll
      for (int j = 0; j < 4; ++j) {
        int p = wr * 64 + m * 16 + kgl * 4 + j;
        float y = mishf(acc[m][nf][j] + bias);
        yt[(M0 + p) * 256 + oc] = f2bf(y);
        sums[nf] += y; sumq[nf] += y * y;
      }
    }
  }
#pragma unroll
  for (int nf = 0; nf < 4; ++nf) {
    float s1 = sums[nf], s2 = sumq[nf];
    s1 += __shfl_xor(s1, 16); s2 += __shfl_xor(s2, 16);
    s1 += __shfl_xor(s1, 32); s2 += __shfl_xor(s2, 32);
    if (lane < 16) {
      int oc = wc * 64 + nf * 16 + lane;
      atomicAdd(&statsA[oc], s1);
      atomicAdd(&statsA[256 + oc], s2);
    }
  }
}

// ---------------- K2: finalize base BN, fold into fused 1x1 weights (64x256) ----------------
__global__ __launch_bounds__(256) void k_fold(const float* __restrict__ statsA,
                                              const float* __restrict__ g_base,
                                              const float* __restrict__ be_base,
                                              const float* __restrict__ W_cls,
                                              const float* __restrict__ b_cls,
                                              const float* __restrict__ W_reg,
                                              const float* __restrict__ b_reg,
                                              unsigned short* __restrict__ W2t,
                                              float* __restrict__ b2) {
  __shared__ float sS[256], sT[256];
  int t = threadIdx.x;
  {
    float cnt = (float)MPIX;
    float m = statsA[t] / cnt;
    float v = fmaxf(statsA[256 + t] / cnt - m * m, 0.f);
    float s = g_base[t] * rsqrtf(v + 1e-5f);
    sS[t] = s;
    sT[t] = be_base[t] - m * s;
  }
  __syncthreads();
  if (t < 64) {
    float bias = 0.f;
    if (t < 36) bias = b_reg[t];
    else if (t < 54) bias = b_cls[t - 36];
    float acc = 0.f;
    for (int ic = 0; ic < 256; ++ic) {
      float w = 0.f;
      if (t < 36) w = W_reg[t * 256 + ic];
      else if (t < 54) w = W_cls[(t - 36) * 256 + ic];
      acc += w * sT[ic];
      W2t[t * 256 + ic] = f2bf(w * sS[ic]);
    }
    b2[t] = bias + acc;
  }
}

// ---------------- K3: fused 1x1 heads GEMM (M=131072, N=64, K=256) + z stats ----------------
__global__ __launch_bounds__(256) void k_mm2(const unsigned short* __restrict__ yt,
                                             const unsigned short* __restrict__ W2t,
                                             const float* __restrict__ b2,
                                             unsigned short* __restrict__ zt,
                                             float* __restrict__ statsZ) {
  __shared__ __align__(16) short Alds[128][32];
  __shared__ __align__(16) short Blds[64][32];
  int t = threadIdx.x, lane = t & 63, w4 = t >> 6;
  size_t pixbase = (size_t)blockIdx.x * 128;

  f32x4 acc[2][4];
#pragma unroll
  for (int m = 0; m < 2; ++m)
#pragma unroll
    for (int nn = 0; nn < 4; ++nn) { f32x4 z = {0.f, 0.f, 0.f, 0.f}; acc[m][nn] = z; }

  int cA0 = (w4 * 2) * 64 + lane;
  int pA0 = cA0 >> 2, qA0 = cA0 & 3;
  int cA1 = cA0 + 64;
  int pA1 = cA1 >> 2, qA1 = cA1 & 3;
  int cB = w4 * 64 + lane;
  int oB = cB >> 2, qB = cB & 3;

  char* aldsb = (char*)&Alds[0][0];
  char* bldsb = (char*)&Blds[0][0];
  int row = lane & 15, kg = lane >> 4;

  for (int s = 0; s < 8; ++s) {
    gl16(yt + (pixbase + pA0) * 256 + s * 32 + qA0 * 8, aldsb + (w4 * 2 + 0) * 1024);
    gl16(yt + (pixbase + pA1) * 256 + s * 32 + qA1 * 8, aldsb + (w4 * 2 + 1) * 1024);
    gl16(W2t + (size_t)oB * 256 + s * 32 + qB * 8, bldsb + w4 * 1024);
    __syncthreads();
    bf16x8 af[2], bfr[4];
#pragma unroll
    for (int m = 0; m < 2; ++m) af[m] = *(const bf16x8*)&Alds[w4 * 32 + m * 16 + row][kg * 8];
#pragma unroll
    for (int nn = 0; nn < 4; ++nn) bfr[nn] = *(const bf16x8*)&Blds[nn * 16 + row][kg * 8];
#pragma unroll
    for (int m = 0; m < 2; ++m)
#pragma unroll
      for (int nn = 0; nn < 4; ++nn)
        acc[m][nn] = __builtin_amdgcn_mfma_f32_16x16x32_bf16(af[m], bfr[nn], acc[m][nn], 0, 0, 0);
    __syncthreads();
  }

  float sums[4] = {0.f, 0.f, 0.f, 0.f}, sumq[4] = {0.f, 0.f, 0.f, 0.f};
#pragma unroll
  for (int nn = 0; nn < 4; ++nn) {
    int oc = nn * 16 + row;
    float bias = b2[oc];
#pragma unroll
    for (int m = 0; m < 2; ++m) {
#pragma unroll
      for (int j = 0; j < 4; ++j) {
        int p = w4 * 32 + m * 16 + kg * 4 + j;
        float v = acc[m][nn][j] + bias;
        zt[(pixbase + p) * 64 + oc] = f2bf(v);
        sums[nn] += v; sumq[nn] += v * v;
      }
    }
  }
#pragma unroll
  for (int nn = 0; nn < 4; ++nn) {
    float s1 = sums[nn], s2 = sumq[nn];
    s1 += __shfl_xor(s1, 16); s2 += __shfl_xor(s2, 16);
    s1 += __shfl_xor(s1, 32); s2 += __shfl_xor(s2, 32);
    if (lane < 16) {
      int oc = nn * 16 + lane;
      atomicAdd(&statsZ[oc], s1);
      atomicAdd(&statsZ[64 + oc], s2);
    }
  }
}

// ---------------- K4: finalize z BN scale/shift ----------------
__global__ __launch_bounds__(64) void k_zstat(const float* __restrict__ statsZ,
                                              const float* __restrict__ g_cls,
                                              const float* __restrict__ be_cls,
                                              const float* __restrict__ g_reg,
                                              const float* __restrict__ be_reg,
                                              float* __restrict__ zsc,
                                              float* __restrict__ zsh) {
  int t = threadIdx.x;  // 64
  float g = 1.f, be = 0.f;
  if (t < 36) { g = g_reg[t]; be = be_reg[t]; }
  else if (t < 54) { g = g_cls[t - 36]; be = be_cls[t - 36]; }
  float cnt = (float)MPIX;
  float m = statsZ[t] / cnt;
  float v = fmaxf(statsZ[64 + t] / cnt - m * m, 0.f);
  float s = g * rsqrtf(v + 1e-5f);
  zsc[t] = s;
  zsh[t] = be - m * s;
}

// ---------------- K5: BN-apply + softmax + anchor decode + outputs ----------------
__global__ __launch_bounds__(256) void k_dec(const unsigned short* __restrict__ zt,
                                             const float* __restrict__ zsc,
                                             const float* __restrict__ zsh,
                                             const int* __restrict__ imgsz,
                                             float* __restrict__ out) {
  int p = blockIdx.x * 256 + threadIdx.x;  // 131072
  float lim = (float)imgsz[0];
  float zn[64];
  {
    const uint4* zp4 = (const uint4*)(zt + (size_t)p * 64);
#pragma unroll
    for (int i = 0; i < 8; ++i) {
      uint4 v = zp4[i];
      unsigned a0 = v.x, a1 = v.y, a2 = v.z, a3 = v.w;
      zn[i * 8 + 0] = bf2f((unsigned short)(a0 & 0xffff));
      zn[i * 8 + 1] = bf2f((unsigned short)(a0 >> 16));
      zn[i * 8 + 2] = bf2f((unsigned short)(a1 & 0xffff));
      zn[i * 8 + 3] = bf2f((unsigned short)(a1 >> 16));
      zn[i * 8 + 4] = bf2f((unsigned short)(a2 & 0xffff));
      zn[i * 8 + 5] = bf2f((unsigned short)(a2 >> 16));
      zn[i * 8 + 6] = bf2f((unsigned short)(a3 & 0xffff));
      zn[i * 8 + 7] = bf2f((unsigned short)(a3 >> 16));
    }
#pragma unroll
    for (int i = 0; i < 54; ++i) zn[i] = zn[i] * zsc[i] + zsh[i];
  }
  int rem = p & 16383, h = rem >> 7, w = rem & 127;
  float fx = 16.f * (float)w, fy = 16.f * (float)h;
  size_t kbase = (size_t)p * 9;
  float* fgout = out;
  float* tsout = out + FGCNT;
  float* roout = out + FGCNT + TSCNT;
#pragma unroll
  for (int a = 0; a < 9; ++a) {
    float x1 = 20.f - 0.5f * AW[a] + fx;
    float y1 = 20.f - 0.5f * AH[a] + fy;
    float x2 = 19.f + 0.5f * AW[a] + fx;
    float y2 = 19.f + 0.5f * AH[a] + fy;
    float cx1 = fminf(fmaxf(x1 + zn[4 * a + 0], 0.f), lim);
    float cy1 = fminf(fmaxf(y1 + zn[4 * a + 1], 0.f), lim);
    float cx2 = fminf(fmaxf(x2 + zn[4 * a + 2], 0.f), lim);
    float cy2 = fminf(fmaxf(y2 + zn[4 * a + 3], 0.f), lim);
    float bw = cx2 - cx1, bh = cy2 - cy1;
    float cx = cx1 + 0.5f * bw, cy = cy1 + 0.5f * bh;
    float aw = AW[a] - 1.f, ah = AH[a] - 1.f;
    float acx = 19.5f + fx, acy = 19.5f + fy;
    float tx = (cx - acx) / aw, ty = (cy - acy) / ah;
    float tw = logf(fmaxf(bw / aw, 1e-30f));
    float th = logf(fmaxf(bh / ah, 1e-30f));
    float s0 = zn[36 + 2 * a], s1 = zn[36 + 2 * a + 1];
    float fg = 1.f / (1.f + expf(s0 - s1));
    fgout[kbase + a] = fg;
    size_t o4 = (kbase + a) * 4;
    tsout[o4 + 0] = tx; tsout[o4 + 1] = ty; tsout[o4 + 2] = tw; tsout[o4 + 3] = th;
    roout[o4 + 0] = cx; roout[o4 + 1] = cy; roout[o4 + 2] = bw; roout[o4 + 3] = bh;
  }
}

// ---------------- launch ----------------
extern "C" void kernel_launch(void* const* d_in, const int* in_sizes, int n_in,
                              void* d_out, int out_size, void* d_ws, size_t ws_size,
                              hipStream_t stream) {
  const float* x   = (const float*)d_in[0];
  const float* Wb  = (const float*)d_in[1];
  const float* bb  = (const float*)d_in[2];
  const float* gb  = (const float*)d_in[3];
  const float* beb = (const float*)d_in[4];
  const float* Wc  = (const float*)d_in[5];
  const float* bc  = (const float*)d_in[6];
  const float* gc  = (const float*)d_in[7];
  const float* bec = (const float*)d_in[8];
  const float* Wr  = (const float*)d_in[9];
  const float* br  = (const float*)d_in[10];
  const float* gr  = (const float*)d_in[11];
  const float* ber = (const float*)d_in[12];
  const int* imgsz = (const int*)d_in[13];

  char* ws = (char*)d_ws;
  const size_t OFF_XTP = 0;                        // 8*130*130*256*2 = 69,222,400
  const size_t OFF_Y   = 69222400;                 // 131072*256*2    = 67,108,864
  const size_t OFF_Z   = 136331264;                // 131072*64*2     = 16,777,216
  const size_t OFF_WT  = 153108480;                // 256*2304*2      =  1,179,648
  const size_t OFF_W2  = 154288128;                // 64*256*2        =     32,768
  const size_t OFF_S   = 154320896;                // small area
  unsigned short* xtp = (unsigned short*)(ws + OFF_XTP);
  unsigned short* yt  = (unsigned short*)(ws + OFF_Y);
  unsigned short* zt  = (unsigned short*)(ws + OFF_Z);
  unsigned short* Wt  = (unsigned short*)(ws + OFF_WT);
  unsigned short* W2t = (unsigned short*)(ws + OFF_W2);
  float* b2     = (float*)(ws + OFF_S);            // 64 f
  float* statsA = (float*)(ws + OFF_S + 256);      // 512 f
  float* statsZ = (float*)(ws + OFF_S + 2304);     // 128 f
  float* zsc    = (float*)(ws + OFF_S + 2816);     // 64 f
  float* zsh    = (float*)(ws + OFF_S + 3072);     // 64 f
  float* out = (float*)d_out;

  hipMemsetAsync(statsA, 0, (512 + 128) * sizeof(float), stream);
  k_wt  <<<2304, 256, 0, stream>>>(Wb, Wt);
  k_tr  <<<8192, 256, 0, stream>>>(x, xtp);
  k_bord<<<516, 256, 0, stream>>>(xtp);
  k_conv<<<1024, 512, 0, stream>>>(xtp, Wt, bb, yt, statsA);
  k_fold<<<1, 256, 0, stream>>>(statsA, gb, beb, Wc, bc, Wr, br, W2t, b2);
  k_mm2 <<<1024, 256, 0, stream>>>(yt, W2t, b2, zt, statsZ);
  k_zstat<<<1, 64, 0, stream>>>(statsZ, gc, bec, gr, ber, zsc, zsh);
  k_dec <<<512, 256, 0, stream>>>(zt, zsc, zsh, imgsz, out);
}

// Round 5
// 498.042 us; speedup vs baseline: 4.1962x; 1.3757x over previous
//
#include <hip/hip_runtime.h>
#include <stdint.h>

// ---------------- types / helpers ----------------
typedef short bf16x8 __attribute__((ext_vector_type(8)));
typedef float f32x4 __attribute__((ext_vector_type(4)));

#define AS1 __attribute__((address_space(1)))
#define AS3 __attribute__((address_space(3)))

static __device__ __forceinline__ void gl16(const void* g, void* l) {
  __builtin_amdgcn_global_load_lds((const AS1 void*)g, (AS3 void*)l, 16, 0, 0);
}

static __device__ __forceinline__ unsigned short f2bf(float f) {
  unsigned u = __float_as_uint(f);
  u = u + 0x7fffu + ((u >> 16) & 1u);
  return (unsigned short)(u >> 16);
}
static __device__ __forceinline__ float bf2f(unsigned short h) {
  return __uint_as_float(((unsigned)h) << 16);
}
static __device__ __forceinline__ float mishf(float x) {
  float sp = fmaxf(x, 0.f) + log1pf(expf(-fabsf(x)));
  float e2 = expf(-2.f * sp);
  float th = (1.f - e2) / (1.f + e2);
  return x * th;
}

// geometry
#define NIMG 8
#define HH 128
#define WW 128
#define HP 130
#define CIN 256
#define MPIX (NIMG * HH * WW)       // 131072
#define KTOT 2304                   // 72 steps of 32
#define FGCNT (MPIX * 9)            // 1179648
#define TSCNT (MPIX * 9 * 4)        // 4718592

__device__ __constant__ float AW[9] = {456.f, 912.f, 1824.f, 320.f, 640.f, 1280.f, 224.f, 448.f, 896.f};
__device__ __constant__ float AH[9] = {224.f, 448.f, 896.f, 320.f, 640.f, 1280.f, 448.f, 896.f, 1792.f};

// ---------------- K0a: conv weights -> Wt2[s][oc][32] bf16, s = kh*24+kw*8+icb ----------------
__global__ __launch_bounds__(256) void k_wt(const float* __restrict__ Wb,
                                            unsigned short* __restrict__ Wt2) {
  int d = blockIdx.x * 256 + threadIdx.x;  // 589824 = 72*256*32
  int c = d & 31, oc = (d >> 5) & 255, s = d >> 13;
  int kh = s / 24, r = s % 24, kw = r >> 3, icb = r & 7;
  int ic = icb * 32 + c;
  Wt2[d] = f2bf(Wb[((oc * 256 + ic) * 3 + kh) * 3 + kw]);
}

// ---------------- K0b: x (NCHW f32) -> xt2 (channel-blocked padded) interior ----------------
// xt2 layout: [icb(8)*8+n][130][130][32] bf16
__global__ __launch_bounds__(256) void k_tr(const float* __restrict__ x,
                                            unsigned short* __restrict__ xt2) {
  __shared__ float tile[32][129];
  int b = blockIdx.x;  // 8 n * 128 h * 8 icb = 8192
  int icb = b & 7, h = (b >> 3) & 127, n = b >> 10;
  int t = threadIdx.x;
  const float* src = x + (((size_t)(n * 256 + icb * 32) * 128 + h) * 128);
#pragma unroll
  for (int i = 0; i < 4; ++i) {
    int idx = t + 256 * i;          // 1024 float4 units
    int w4 = idx & 31, ic = idx >> 5;
    float4 v = *(const float4*)(src + (size_t)ic * 16384 + w4 * 4);
    tile[ic][w4 * 4 + 0] = v.x; tile[ic][w4 * 4 + 1] = v.y;
    tile[ic][w4 * 4 + 2] = v.z; tile[ic][w4 * 4 + 3] = v.w;
  }
  __syncthreads();
#pragma unroll
  for (int i = 0; i < 8; ++i) {
    int idx = t + 256 * i;          // 2048 bf16-pairs
    int icp = idx & 15, w = idx >> 4;
    unsigned lo = f2bf(tile[icp * 2][w]);
    unsigned hi = f2bf(tile[icp * 2 + 1][w]);
    size_t pix = ((size_t)(icb * 8 + n) * HP + (h + 1)) * HP + (w + 1);
    *(unsigned*)(xt2 + pix * 32 + icp * 2) = lo | (hi << 16);
  }
}

// ---------------- K0c: zero padded borders of xt2 ----------------
__global__ __launch_bounds__(256) void k_bord(unsigned short* __restrict__ xt2) {
  int tid = blockIdx.x * 256 + threadIdx.x;  // 64 planes * 516 border pix * 4 chunks = 132096
  int chunk = tid & 3, pix = tid >> 2;
  int nn = pix / 516, bp = pix % 516;        // nn = icb*8+n plane
  int hp, wp;
  if (bp < 130) { hp = 0; wp = bp; }
  else if (bp < 260) { hp = 129; wp = bp - 130; }
  else { int r = bp - 260; hp = 1 + (r >> 1); wp = (r & 1) ? 129 : 0; }
  size_t off = (((size_t)nn * HP + hp) * HP + wp) * 32 + chunk * 8;
  uint4 z = {0u, 0u, 0u, 0u};
  *(uint4*)(xt2 + off) = z;
}

// ---------------- K1: conv3x3 implicit GEMM, coalesced + dbuf 2-phase ----------------
// M=131072, N=256, K=2304 (72 steps: (kh,kw,icb)). BM=128 (one row), BN=256, 8 waves.
// Staging now fully coalesced: each wave's 64 lanes load one contiguous 1KB run
// (channel-blocked layouts). LDS chunk-XOR swizzle q' = q ^ (pix&3) ^ ((pix>>2)&3)
// applied via pre-swizzled SOURCE (linear global_load_lds dest) + swizzled READ.
// Double-buffered, 1 barrier + vmcnt(0)/step: stage(t+1) hides behind MFMA(t).
__global__ __launch_bounds__(512) void k_conv(const unsigned short* __restrict__ xt2,
                                              const unsigned short* __restrict__ Wt2,
                                              const float* __restrict__ b_base,
                                              unsigned short* __restrict__ yt2,
                                              float* __restrict__ statsA) {
  __shared__ __align__(16) char lds[49152];   // A: 2x8KB, B: 2x16KB
  char* aldsb = lds;
  char* bldsb = lds + 16384;
  int t = threadIdx.x;
  int lane = t & 63, w4 = t >> 6;
  int wr = w4 >> 2, wc = w4 & 3;               // 2M x 4N wave grid, wave tile 64x64
  int row16 = lane & 15, kgl = lane >> 4;
  int mq = (row16 & 3) ^ ((row16 >> 2) & 3);   // read-side swizzle (== store-side, proven)
  int kq16 = (kgl ^ mq) * 16;                  // byte offset of k-chunk within 64B slot

  int bid = blockIdx.x;                        // 1024 blocks, %8==0 -> bijective
  int swz = (bid & 7) * 128 + (bid >> 3);
  int n = swz >> 7, h0 = swz & 127;
  size_t M0 = (size_t)swz * 128;

  f32x4 acc[4][4];
#pragma unroll
  for (int m = 0; m < 4; ++m)
#pragma unroll
    for (int nf = 0; nf < 4; ++nf) { f32x4 z = {0.f, 0.f, 0.f, 0.f}; acc[m][nf] = z; }

  // staging invariants: thread t handles A-chunk t (pix=t>>2) and B-chunks t, t+512
  int pixA = t >> 2;                           // == ocB (0..127)
  int qA = (t & 3) ^ ((pixA & 3) ^ ((pixA >> 2) & 3));  // pre-swizzled source quarter
  char* dA = aldsb + w4 * 1024;
  char* dB0 = bldsb + w4 * 1024;
  char* dB1 = bldsb + 8192 + w4 * 1024;

  auto STAGE = [&](int sv, int c_) {
    int kh_ = sv / 24, r_ = sv % 24, kw_ = r_ >> 3, icb_ = r_ & 7;
    const unsigned short* pa = xt2 +
        (((size_t)(icb_ * 8 + n) * HP + h0 + kh_) * HP + pixA + kw_) * 32 + qA * 8;
    gl16(pa, dA + c_ * 8192);
    const unsigned short* pb = Wt2 + ((size_t)sv * 256 + pixA) * 32 + qA * 8;
    gl16(pb, dB0 + c_ * 16384);
    gl16(pb + 4096, dB1 + c_ * 16384);         // +128 oc
  };

  STAGE(0, 0);
  asm volatile("s_waitcnt vmcnt(0)" ::: "memory");
  __builtin_amdgcn_s_barrier();
  __builtin_amdgcn_sched_barrier(0);

  int cur = 0;
  for (int s2 = 0; s2 < 72; ++s2) {
    if (s2 < 71) STAGE(s2 + 1, cur ^ 1);
    const char* ab = aldsb + cur * 8192;
    const char* bb2 = bldsb + cur * 16384;
    bf16x8 af[4], bfr[4];
#pragma unroll
    for (int m = 0; m < 4; ++m)
      af[m] = *(const bf16x8*)(ab + (wr * 64 + m * 16 + row16) * 64 + kq16);
#pragma unroll
    for (int nf = 0; nf < 4; ++nf)
      bfr[nf] = *(const bf16x8*)(bb2 + (wc * 64 + nf * 16 + row16) * 64 + kq16);
    asm volatile("s_waitcnt lgkmcnt(0)" ::: "memory");
    __builtin_amdgcn_sched_barrier(0);
    __builtin_amdgcn_s_setprio(1);
#pragma unroll
    for (int m = 0; m < 4; ++m)
#pragma unroll
      for (int nf = 0; nf < 4; ++nf)
        acc[m][nf] = __builtin_amdgcn_mfma_f32_16x16x32_bf16(af[m], bfr[nf], acc[m][nf], 0, 0, 0);
    __builtin_amdgcn_s_setprio(0);
    if (s2 < 71) {
      asm volatile("s_waitcnt vmcnt(0)" ::: "memory");
      __builtin_amdgcn_s_barrier();
      __builtin_amdgcn_sched_barrier(0);
    }
    cur ^= 1;
  }

  // epilogue: bias + mish, store channel-blocked yt2[oc>>5][pix][oc&31], stats
  float sums[4] = {0.f, 0.f, 0.f, 0.f}, sumq[4] = {0.f, 0.f, 0.f, 0.f};
#pragma unroll
  for (int nf = 0; nf < 4; ++nf) {
    int oc = wc * 64 + nf * 16 + row16;
    float bias = b_base[oc];
    size_t obase = (size_t)(oc >> 5) * MPIX * 32 + (oc & 31);
#pragma unroll
    for (int m = 0; m < 4; ++m) {
#pragma unroll
      for (int j = 0; j < 4; ++j) {
        int p = wr * 64 + m * 16 + kgl * 4 + j;
        float y = mishf(acc[m][nf][j] + bias);
        yt2[obase + (M0 + p) * 32] = f2bf(y);
        sums[nf] += y; sumq[nf] += y * y;
      }
    }
  }
#pragma unroll
  for (int nf = 0; nf < 4; ++nf) {
    float s1 = sums[nf], s2 = sumq[nf];
    s1 += __shfl_xor(s1, 16); s2 += __shfl_xor(s2, 16);
    s1 += __shfl_xor(s1, 32); s2 += __shfl_xor(s2, 32);
    if (lane < 16) {
      int oc = wc * 64 + nf * 16 + lane;
      atomicAdd(&statsA[oc], s1);
      atomicAdd(&statsA[256 + oc], s2);
    }
  }
}

// ---------------- K2: finalize base BN, fold into fused 1x1 weights ----------------
// W2t2 layout: [s(8)][64 oc][32] bf16
__global__ __launch_bounds__(256) void k_fold(const float* __restrict__ statsA,
                                              const float* __restrict__ g_base,
                                              const float* __restrict__ be_base,
                                              const float* __restrict__ W_cls,
                                              const float* __restrict__ b_cls,
                                              const float* __restrict__ W_reg,
                                              const float* __restrict__ b_reg,
                                              unsigned short* __restrict__ W2t2,
                                              float* __restrict__ b2) {
  __shared__ float sS[256], sT[256];
  int t = threadIdx.x;
  {
    float cnt = (float)MPIX;
    float m = statsA[t] / cnt;
    float v = fmaxf(statsA[256 + t] / cnt - m * m, 0.f);
    float s = g_base[t] * rsqrtf(v + 1e-5f);
    sS[t] = s;
    sT[t] = be_base[t] - m * s;
  }
  __syncthreads();
  if (t < 64) {
    float bias = 0.f;
    if (t < 36) bias = b_reg[t];
    else if (t < 54) bias = b_cls[t - 36];
    float acc = 0.f;
    for (int ic = 0; ic < 256; ++ic) {
      float w = 0.f;
      if (t < 36) w = W_reg[t * 256 + ic];
      else if (t < 54) w = W_cls[(t - 36) * 256 + ic];
      acc += w * sT[ic];
      W2t2[((size_t)(ic >> 5) * 64 + t) * 32 + (ic & 31)] = f2bf(w * sS[ic]);
    }
    b2[t] = bias + acc;
  }
}

// ---------------- K3: fused 1x1 heads GEMM (M=131072, N=64, K=256) + z stats ----------------
__global__ __launch_bounds__(256) void k_mm2(const unsigned short* __restrict__ yt2,
                                             const unsigned short* __restrict__ W2t2,
                                             const float* __restrict__ b2,
                                             unsigned short* __restrict__ zt,
                                             float* __restrict__ statsZ) {
  __shared__ __align__(16) char lds2[12288];   // A 8KB, B 4KB
  char* a2 = lds2;
  char* b2l = lds2 + 8192;
  int t = threadIdx.x, lane = t & 63, w4 = t >> 6;
  int row16 = lane & 15, kgl = lane >> 4;
  int mq = (row16 & 3) ^ ((row16 >> 2) & 3);
  int kq16 = (kgl ^ mq) * 16;
  size_t pixbase = (size_t)blockIdx.x * 128;

  f32x4 acc[2][4];
#pragma unroll
  for (int m = 0; m < 2; ++m)
#pragma unroll
    for (int nn = 0; nn < 4; ++nn) { f32x4 z = {0.f, 0.f, 0.f, 0.f}; acc[m][nn] = z; }

  int pixA = t >> 2;                           // 0..63 for A-chunk t; +64 for t+256
  int qAa = (t & 3) ^ ((pixA & 3) ^ ((pixA >> 2) & 3));
  char* dA0 = a2 + w4 * 1024;
  char* dA1 = a2 + 4096 + w4 * 1024;
  char* dB = b2l + w4 * 1024;

  for (int s = 0; s < 8; ++s) {
    const unsigned short* pa = yt2 + ((size_t)s * MPIX + pixbase + pixA) * 32 + qAa * 8;
    gl16(pa, dA0);
    gl16(pa + 64 * 32, dA1);                   // pix + 64, same swizzle class
    const unsigned short* pb = W2t2 + ((size_t)s * 64 + pixA) * 32 + qAa * 8;  // pixA=oc<64? t>>2 in 0..63
    gl16(pb, dB);
    __syncthreads();
    bf16x8 af[2], bfr[4];
#pragma unroll
    for (int m = 0; m < 2; ++m)
      af[m] = *(const bf16x8*)(a2 + (w4 * 32 + m * 16 + row16) * 64 + kq16);
#pragma unroll
    for (int nn = 0; nn < 4; ++nn)
      bfr[nn] = *(const bf16x8*)(b2l + (nn * 16 + row16) * 64 + kq16);
#pragma unroll
    for (int m = 0; m < 2; ++m)
#pragma unroll
      for (int nn = 0; nn < 4; ++nn)
        acc[m][nn] = __builtin_amdgcn_mfma_f32_16x16x32_bf16(af[m], bfr[nn], acc[m][nn], 0, 0, 0);
    __syncthreads();
  }

  float sums[4] = {0.f, 0.f, 0.f, 0.f}, sumq[4] = {0.f, 0.f, 0.f, 0.f};
#pragma unroll
  for (int nn = 0; nn < 4; ++nn) {
    int oc = nn * 16 + row16;
    float bias = b2[oc];
#pragma unroll
    for (int m = 0; m < 2; ++m) {
#pragma unroll
      for (int j = 0; j < 4; ++j) {
        int p = w4 * 32 + m * 16 + kgl * 4 + j;
        float v = acc[m][nn][j] + bias;
        zt[(pixbase + p) * 64 + oc] = f2bf(v);
        sums[nn] += v; sumq[nn] += v * v;
      }
    }
  }
#pragma unroll
  for (int nn = 0; nn < 4; ++nn) {
    float s1 = sums[nn], s2 = sumq[nn];
    s1 += __shfl_xor(s1, 16); s2 += __shfl_xor(s2, 16);
    s1 += __shfl_xor(s1, 32); s2 += __shfl_xor(s2, 32);
    if (lane < 16) {
      int oc = nn * 16 + lane;
      atomicAdd(&statsZ[oc], s1);
      atomicAdd(&statsZ[64 + oc], s2);
    }
  }
}

// ---------------- K4: finalize z BN scale/shift ----------------
__global__ __launch_bounds__(64) void k_zstat(const float* __restrict__ statsZ,
                                              const float* __restrict__ g_cls,
                                              const float* __restrict__ be_cls,
                                              const float* __restrict__ g_reg,
                                              const float* __restrict__ be_reg,
                                              float* __restrict__ zsc,
                                              float* __restrict__ zsh) {
  int t = threadIdx.x;  // 64
  float g = 1.f, be = 0.f;
  if (t < 36) { g = g_reg[t]; be = be_reg[t]; }
  else if (t < 54) { g = g_cls[t - 36]; be = be_cls[t - 36]; }
  float cnt = (float)MPIX;
  float m = statsZ[t] / cnt;
  float v = fmaxf(statsZ[64 + t] / cnt - m * m, 0.f);
  float s = g * rsqrtf(v + 1e-5f);
  zsc[t] = s;
  zsh[t] = be - m * s;
}

// ---------------- K5: BN-apply + softmax + anchor decode + outputs ----------------
__global__ __launch_bounds__(256) void k_dec(const unsigned short* __restrict__ zt,
                                             const float* __restrict__ zsc,
                                             const float* __restrict__ zsh,
                                             const int* __restrict__ imgsz,
                                             float* __restrict__ out) {
  int p = blockIdx.x * 256 + threadIdx.x;  // 131072
  float lim = (float)imgsz[0];
  float zn[64];
  {
    const uint4* zp4 = (const uint4*)(zt + (size_t)p * 64);
#pragma unroll
    for (int i = 0; i < 8; ++i) {
      uint4 v = zp4[i];
      unsigned a0 = v.x, a1 = v.y, a2 = v.z, a3 = v.w;
      zn[i * 8 + 0] = bf2f((unsigned short)(a0 & 0xffff));
      zn[i * 8 + 1] = bf2f((unsigned short)(a0 >> 16));
      zn[i * 8 + 2] = bf2f((unsigned short)(a1 & 0xffff));
      zn[i * 8 + 3] = bf2f((unsigned short)(a1 >> 16));
      zn[i * 8 + 4] = bf2f((unsigned short)(a2 & 0xffff));
      zn[i * 8 + 5] = bf2f((unsigned short)(a2 >> 16));
      zn[i * 8 + 6] = bf2f((unsigned short)(a3 & 0xffff));
      zn[i * 8 + 7] = bf2f((unsigned short)(a3 >> 16));
    }
#pragma unroll
    for (int i = 0; i < 54; ++i) zn[i] = zn[i] * zsc[i] + zsh[i];
  }
  int rem = p & 16383, h = rem >> 7, w = rem & 127;
  float fx = 16.f * (float)w, fy = 16.f * (float)h;
  size_t kbase = (size_t)p * 9;
  float* fgout = out;
  float* tsout = out + FGCNT;
  float* roout = out + FGCNT + TSCNT;
#pragma unroll
  for (int a = 0; a < 9; ++a) {
    float x1 = 20.f - 0.5f * AW[a] + fx;
    float y1 = 20.f - 0.5f * AH[a] + fy;
    float x2 = 19.f + 0.5f * AW[a] + fx;
    float y2 = 19.f + 0.5f * AH[a] + fy;
    float cx1 = fminf(fmaxf(x1 + zn[4 * a + 0], 0.f), lim);
    float cy1 = fminf(fmaxf(y1 + zn[4 * a + 1], 0.f), lim);
    float cx2 = fminf(fmaxf(x2 + zn[4 * a + 2], 0.f), lim);
    float cy2 = fminf(fmaxf(y2 + zn[4 * a + 3], 0.f), lim);
    float bw = cx2 - cx1, bh = cy2 - cy1;
    float cx = cx1 + 0.5f * bw, cy = cy1 + 0.5f * bh;
    float aw = AW[a] - 1.f, ah = AH[a] - 1.f;
    float acx = 19.5f + fx, acy = 19.5f + fy;
    float tx = (cx - acx) / aw, ty = (cy - acy) / ah;
    float tw = logf(fmaxf(bw / aw, 1e-30f));
    float th = logf(fmaxf(bh / ah, 1e-30f));
    float s0 = zn[36 + 2 * a], s1 = zn[36 + 2 * a + 1];
    float fg = 1.f / (1.f + expf(s0 - s1));
    fgout[kbase + a] = fg;
    size_t o4 = (kbase + a) * 4;
    tsout[o4 + 0] = tx; tsout[o4 + 1] = ty; tsout[o4 + 2] = tw; tsout[o4 + 3] = th;
    roout[o4 + 0] = cx; roout[o4 + 1] = cy; roout[o4 + 2] = bw; roout[o4 + 3] = bh;
  }
}

// ---------------- launch ----------------
extern "C" void kernel_launch(void* const* d_in, const int* in_sizes, int n_in,
                              void* d_out, int out_size, void* d_ws, size_t ws_size,
                              hipStream_t stream) {
  const float* x   = (const float*)d_in[0];
  const float* Wb  = (const float*)d_in[1];
  const float* bb  = (const float*)d_in[2];
  const float* gb  = (const float*)d_in[3];
  const float* beb = (const float*)d_in[4];
  const float* Wc  = (const float*)d_in[5];
  const float* bc  = (const float*)d_in[6];
  const float* gc  = (const float*)d_in[7];
  const float* bec = (const float*)d_in[8];
  const float* Wr  = (const float*)d_in[9];
  const float* br  = (const float*)d_in[10];
  const float* gr  = (const float*)d_in[11];
  const float* ber = (const float*)d_in[12];
  const int* imgsz = (const int*)d_in[13];

  char* ws = (char*)d_ws;
  const size_t OFF_XTP = 0;                        // 64*130*130*32*2 = 69,222,400
  const size_t OFF_Y   = 69222400;                 // 8*131072*32*2   = 67,108,864
  const size_t OFF_Z   = 136331264;                // 131072*64*2     = 16,777,216
  const size_t OFF_WT  = 153108480;                // 72*256*32*2     =  1,179,648
  const size_t OFF_W2  = 154288128;                // 8*64*32*2       =     32,768
  const size_t OFF_S   = 154320896;                // small area
  unsigned short* xt2  = (unsigned short*)(ws + OFF_XTP);
  unsigned short* yt2  = (unsigned short*)(ws + OFF_Y);
  unsigned short* zt   = (unsigned short*)(ws + OFF_Z);
  unsigned short* Wt2  = (unsigned short*)(ws + OFF_WT);
  unsigned short* W2t2 = (unsigned short*)(ws + OFF_W2);
  float* b2     = (float*)(ws + OFF_S);            // 64 f
  float* statsA = (float*)(ws + OFF_S + 256);      // 512 f
  float* statsZ = (float*)(ws + OFF_S + 2304);     // 128 f
  float* zsc    = (float*)(ws + OFF_S + 2816);     // 64 f
  float* zsh    = (float*)(ws + OFF_S + 3072);     // 64 f
  float* out = (float*)d_out;

  hipMemsetAsync(statsA, 0, (512 + 128) * sizeof(float), stream);
  k_wt  <<<2304, 256, 0, stream>>>(Wb, Wt2);
  k_tr  <<<8192, 256, 0, stream>>>(x, xt2);
  k_bord<<<516, 256, 0, stream>>>(xt2);
  k_conv<<<1024, 512, 0, stream>>>(xt2, Wt2, bb, yt2, statsA);
  k_fold<<<1, 256, 0, stream>>>(statsA, gb, beb, Wc, bc, Wr, br, W2t2, b2);
  k_mm2 <<<1024, 256, 0, stream>>>(yt2, W2t2, b2, zt, statsZ);
  k_zstat<<<1, 64, 0, stream>>>(statsZ, gc, bec, gr, ber, zsc, zsh);
  k_dec <<<512, 256, 0, stream>>>(zt, zsc, zsh, imgsz, out);
}